// Round 8
// baseline (292.898 us; speedup 1.0000x reference)
//
#include <hip/hip_runtime.h>
#include <math.h>

// IDMRFLoss on MI355X — R8: 16B/lane sim stores+loads (paired-u layout),
// restructured colsum (4 superblocks/block, shuffle-reduced atomics) and
// rowmax (16 rows/wave, 1KB reads, 1 atomic/block), zero_acc folded into
// colmax_reduce.
//
// Layer 0 (relu3_2): B=4, C=256, S=4096, weight 1.0
// Layer 1 (relu4_2): B=4, C=512, S=1024, weight 2.0 (style + content)
//
// Swizzled operand layout (per batch-slot, matrix [S][K] bf16):
//   elem(row,k) at ((row>>4)*(K/8) + (k>>3))*128 + (row&15)*8 + (k&7)
// sim blocked bf16 layout v2 (per 128x128 block at (by,bx)):
//   chunk16B at (by*nQB+bx)*16384 + slot*4096 + (t*2+U)*512 + lane*8, j in 0..7:
//     du=j>>2, r=j&3
//     p = by*128 + (slot&1)*64 + t*16 + (lane>>4)*4 + r
//     q = bx*128 + (slot>>1)*64 + U*32 + du*16 + (lane&15)
//
// Math (per z): c1 = 1/((1-colmax)/2+eps); log2 domain: c1L=c1*log2e,
// c0L=(2-c1)*log2e; colsum_q = sum_p 2^(c0L+c1L*v); fold c0L' = c0L-log2(colsum);
// kmax_p = 2^(max_q (c0L'+c1L*v)).

#define MRF_EPS 1e-5f
#define LOG2E 1.44269504088896340736f

typedef __attribute__((ext_vector_type(8))) short bf16x8;
typedef __attribute__((ext_vector_type(4))) float f32x4;
typedef unsigned short ushort_t;
struct __align__(16) ushort8_t { ushort_t v[8]; };

__device__ __forceinline__ ushort_t f2bf(float x) {
    unsigned u = __float_as_uint(x);
    u += 0x7FFFu + ((u >> 16) & 1u);
    return (ushort_t)(u >> 16);
}
__device__ __forceinline__ float bf2f(ushort_t u) {
    return __uint_as_float(((unsigned)u) << 16);
}

// ---- stats: per position mean(tar), 1/||g-m||, 1/||t-m|| (single pass) ----
__global__ __launch_bounds__(256) void stats_kernel(
    const float* __restrict__ gen, const float* __restrict__ tar,
    float* __restrict__ mean, float* __restrict__ rg, float* __restrict__ rt,
    int C, int S) {
    int tid = threadIdx.x, pq = tid & 3, cs = tid >> 2;
    int b = blockIdx.y;
    int s0 = blockIdx.x * 16 + pq * 4;
    const float* g = gen + (size_t)b * C * S + s0;
    const float* t = tar + (size_t)b * C * S + s0;

    f32x4 st = {0.f, 0.f, 0.f, 0.f}, st2 = st, sg = st, sg2 = st;
    for (int c = cs; c < C; c += 64) {
        f32x4 tv = *(const f32x4*)(t + (size_t)c * S);
        f32x4 gv = *(const f32x4*)(g + (size_t)c * S);
        st += tv; st2 += tv * tv; sg += gv; sg2 += gv * gv;
    }
    __shared__ f32x4 red[4][4][64];
    __shared__ f32x4 red2[4][4][4];
    red[0][pq][cs] = st; red[1][pq][cs] = st2; red[2][pq][cs] = sg; red[3][pq][cs] = sg2;
    __syncthreads();
    if (tid < 64) {
        int s_ = tid >> 4, p_ = (tid >> 2) & 3, part = tid & 3;
        f32x4 s = red[s_][p_][part * 16];
#pragma unroll
        for (int j = 1; j < 16; j++) s += red[s_][p_][part * 16 + j];
        red2[s_][p_][part] = s;
    }
    __syncthreads();
    if (tid < 4) {
        f32x4 sts = red2[0][tid][0] + red2[0][tid][1] + red2[0][tid][2] + red2[0][tid][3];
        f32x4 st2s = red2[1][tid][0] + red2[1][tid][1] + red2[1][tid][2] + red2[1][tid][3];
        f32x4 sgs = red2[2][tid][0] + red2[2][tid][1] + red2[2][tid][2] + red2[2][tid][3];
        f32x4 sg2s = red2[3][tid][0] + red2[3][tid][1] + red2[3][tid][2] + red2[3][tid][3];
        f32x4 m, vrt, vrg;
        float invC = 1.f / (float)C;
#pragma unroll
        for (int e = 0; e < 4; e++) {
            float mm = sts[e] * invC;
            m[e] = mm;
            vrt[e] = rsqrtf(st2s[e] - mm * sts[e]);
            vrg[e] = rsqrtf(sg2s[e] - 2.f * mm * sgs[e] + mm * sts[e]);
        }
        int idx = b * S + blockIdx.x * 16 + tid * 4;
        *(f32x4*)(mean + idx) = m;
        *(f32x4*)(rt + idx) = vrt;
        *(f32x4*)(rg + idx) = vrg;
    }
}

// ---- apply: normalize + transpose -> swizzled MFMA layout bf16 (slot z) ----
__global__ __launch_bounds__(256) void apply_kernel(
    const float* __restrict__ gen, const float* __restrict__ tar,
    const float* __restrict__ mean, const float* __restrict__ rg, const float* __restrict__ rt,
    ushort_t* __restrict__ gnT, ushort_t* __restrict__ tnT, int C, int S, int batchBase) {
    int tid = threadIdx.x;
    int slot = blockIdx.z, b = batchBase + slot;
    int s0 = blockIdx.x * 64, c0 = blockIdx.y * 64;
    const float* g = gen + (size_t)b * C * S;
    const float* t = tar + (size_t)b * C * S;
    int tx = tid & 63, tw = tid >> 6;
    int sidx = b * S + s0 + tx;
    float m = mean[sidx], rgv = rg[sidx], rtv = rt[sidx];

    __shared__ ushort_t tg[64][72], tt_[64][72];
#pragma unroll
    for (int i = 0; i < 16; i++) {
        int cl = tw * 16 + i;
        float gv = g[(size_t)(c0 + cl) * S + s0 + tx];
        float tv = t[(size_t)(c0 + cl) * S + s0 + tx];
        tg[tx][cl] = f2bf((gv - m) * rgv);
        tt_[tx][cl] = f2bf((tv - m) * rtv);
    }
    __syncthreads();
    int KC = C >> 3;
#pragma unroll
    for (int j = 0; j < 2; j++) {
        int p = j * 256 + tid;
        int s = p & 63, ch = p >> 6;
        int row = s0 + s;
        int r16 = row >> 4, lm = row & 15;
        size_t off = (size_t)slot * S * C + (((size_t)r16 * KC + (c0 >> 3) + ch) * 16 + lm) * 8;
        *(ushort8_t*)(gnT + off) = *(const ushort8_t*)&tg[s][ch * 8];
        *(ushort8_t*)(tnT + off) = *(const ushort8_t*)&tt_[s][ch * 8];
    }
}

// ---- MFMA GEMM, LDS-free, no atomics: sim (16B paired stores) + colmax partials ----
template <int K>
__global__ __launch_bounds__(256) void gemm_mfma(
    const ushort_t* __restrict__ A, const ushort_t* __restrict__ B,
    ushort_t* __restrict__ sim, float* __restrict__ cmPart,
    int S, size_t abStride, size_t simStride, size_t cmStride) {
    int z = blockIdx.z;
    A += (size_t)z * abStride; B += (size_t)z * abStride;
    sim += (size_t)z * simStride; cmPart += (size_t)z * cmStride;

    const int tid = threadIdx.x;
    const int lane = tid & 63, wave = tid >> 6;
    const int wm = (wave & 1) * 64, wn = (wave >> 1) * 64;
    const int lm = lane & 15, quad = lane >> 4;
    const int p0 = blockIdx.y * 128, q0 = blockIdx.x * 128;

    constexpr int KC = K / 8;
    constexpr int KS = K / 32;

    const ushort_t* Ab = A + ((size_t)((p0 + wm) >> 4) * KC + quad) * 128 + lm * 8;
    const ushort_t* Bb = B + ((size_t)((q0 + wn) >> 4) * KC + quad) * 128 + lm * 8;

    f32x4 acc[4][4];
#pragma unroll
    for (int t = 0; t < 4; t++)
#pragma unroll
        for (int u = 0; u < 4; u++) acc[t][u] = (f32x4){0.f, 0.f, 0.f, 0.f};

    bf16x8 a0[4], b0[4], a1[4], b1[4];
#pragma unroll
    for (int t = 0; t < 4; t++) {
        a0[t] = *(const bf16x8*)(Ab + (size_t)(t * KC) * 128);
        b0[t] = *(const bf16x8*)(Bb + (size_t)(t * KC) * 128);
    }
#pragma unroll
    for (int ks = 0; ks < KS; ks += 2) {
#pragma unroll
        for (int t = 0; t < 4; t++) {
            a1[t] = *(const bf16x8*)(Ab + (size_t)(t * KC + (ks + 1) * 4) * 128);
            b1[t] = *(const bf16x8*)(Bb + (size_t)(t * KC + (ks + 1) * 4) * 128);
        }
#pragma unroll
        for (int t = 0; t < 4; t++)
#pragma unroll
            for (int u = 0; u < 4; u++)
                acc[t][u] = __builtin_amdgcn_mfma_f32_16x16x32_bf16(a0[t], b0[u], acc[t][u], 0, 0, 0);
        if (ks + 2 < KS) {
#pragma unroll
            for (int t = 0; t < 4; t++) {
                a0[t] = *(const bf16x8*)(Ab + (size_t)(t * KC + (ks + 2) * 4) * 128);
                b0[t] = *(const bf16x8*)(Bb + (size_t)(t * KC + (ks + 2) * 4) * 128);
            }
        }
#pragma unroll
        for (int t = 0; t < 4; t++)
#pragma unroll
            for (int u = 0; u < 4; u++)
                acc[t][u] = __builtin_amdgcn_mfma_f32_16x16x32_bf16(a1[t], b1[u], acc[t][u], 0, 0, 0);
    }

    // epilogue: pack u-pairs to ushort8 (16B/lane stores) + colmax partials
    int nQB = S >> 7;
    ushort_t* tile = sim + ((size_t)(blockIdx.y * nQB + blockIdx.x)) * 16384
                   + (size_t)(wave * 4096 + lane * 8);
    float cmax[4] = {-INFINITY, -INFINITY, -INFINITY, -INFINITY};
#pragma unroll
    for (int t = 0; t < 4; t++)
#pragma unroll
        for (int U = 0; U < 2; U++) {
            ushort8_t o;
#pragma unroll
            for (int du = 0; du < 2; du++) {
                f32x4 v = acc[t][U * 2 + du];
                float mx = -INFINITY;
#pragma unroll
                for (int r = 0; r < 4; r++) {
                    ushort_t w = f2bf(v[r]);
                    o.v[du * 4 + r] = w;
                    mx = fmaxf(mx, bf2f(w));
                }
                cmax[U * 2 + du] = fmaxf(cmax[U * 2 + du], mx);
            }
            *(ushort8_t*)(tile + (t * 2 + U) * 512) = o;
        }
    int r = blockIdx.y * 2 + (wave & 1);
#pragma unroll
    for (int u = 0; u < 4; u++) {
        float m = cmax[u];
        m = fmaxf(m, __shfl_xor(m, 16, 64));
        m = fmaxf(m, __shfl_xor(m, 32, 64));
        if (lane < 16) cmPart[(size_t)r * S + q0 + wn + u * 16 + lane] = m;
    }
}

// ---- reduce colmax partials -> log2 coef {c0L,c1L}; zero colsum + acc slot ----
__global__ __launch_bounds__(256) void colmax_reduce(
    const float* __restrict__ cmPart, float2* __restrict__ coef,
    float* __restrict__ colsum, float* __restrict__ accSlot,
    int S, int R, size_t cmStride) {
    int z = blockIdx.y;
    if (blockIdx.x == 0 && threadIdx.x == 0) accSlot[z] = 0.f;
    cmPart += (size_t)z * cmStride; coef += (size_t)z * S; colsum += (size_t)z * S;
    int q = blockIdx.x * 256 + threadIdx.x;
    float m = cmPart[q];
    for (int r = 1; r < R; r++) m = fmaxf(m, cmPart[(size_t)r * S + q]);
    float c1 = 1.f / ((1.f - m) * 0.5f + MRF_EPS);
    coef[q] = make_float2((2.f - c1) * LOG2E, c1 * LOG2E);
    colsum[q] = 0.f;
}

// ---- column sums of dist: 16B reads, 4 p-superblocks/block, shuffle-reduced atomics ----
// grid (S/128, S/512, z), block 256
__global__ __launch_bounds__(256) void colsum_kernel(
    const ushort_t* __restrict__ sim, const float2* __restrict__ coef,
    float* __restrict__ colsum, int S, size_t simStride) {
    int z = blockIdx.z;
    sim += (size_t)z * simStride; coef += (size_t)z * S; colsum += (size_t)z * S;
    int tid = threadIdx.x, lane = tid & 63, slot = tid >> 6;
    int lm = lane & 15;
    int bx = blockIdx.x, qh = slot >> 1;
    int nQB = S >> 7;

    float c0[2][2], c1[2][2];
#pragma unroll
    for (int U = 0; U < 2; U++)
#pragma unroll
        for (int du = 0; du < 2; du++) {
            float2 cc = coef[bx * 128 + qh * 64 + U * 32 + du * 16 + lm];
            c0[U][du] = cc.x; c1[U][du] = cc.y;
        }

    float s[2][2] = {{0.f, 0.f}, {0.f, 0.f}};
    const ushort_t* base = sim + (size_t)(slot * 4096 + lane * 8);
    for (int byi = 0; byi < 4; byi++) {
        int by = blockIdx.y * 4 + byi;
        const ushort_t* tb = base + ((size_t)(by * nQB + bx)) * 16384;
#pragma unroll
        for (int t = 0; t < 4; t++)
#pragma unroll
            for (int U = 0; U < 2; U++) {
                ushort8_t w = *(const ushort8_t*)(tb + (t * 2 + U) * 512);
#pragma unroll
                for (int du = 0; du < 2; du++) {
                    s[U][du] += exp2f(c0[U][du] + c1[U][du] * bf2f(w.v[du * 4 + 0]))
                              + exp2f(c0[U][du] + c1[U][du] * bf2f(w.v[du * 4 + 1]))
                              + exp2f(c0[U][du] + c1[U][du] * bf2f(w.v[du * 4 + 2]))
                              + exp2f(c0[U][du] + c1[U][du] * bf2f(w.v[du * 4 + 3]));
                }
            }
    }
    // reduce across quads (lanes xor 16,32 share q), then atomic from quad 0
#pragma unroll
    for (int U = 0; U < 2; U++)
#pragma unroll
        for (int du = 0; du < 2; du++) {
            float v = s[U][du];
            v += __shfl_xor(v, 16, 64);
            v += __shfl_xor(v, 32, 64);
            if (lane < 16)
                atomicAdd(colsum + bx * 128 + qh * 64 + U * 32 + du * 16 + lm, v);
        }
}

// ---- fold colsum into coef: c0L' = c0L - log2(colsum) ----
__global__ __launch_bounds__(256) void coef_fold(
    float2* __restrict__ coef, const float* __restrict__ colsum, int S) {
    int z = blockIdx.y;
    coef += (size_t)z * S; colsum += (size_t)z * S;
    int q = blockIdx.x * 256 + threadIdx.x;
    coef[q].x -= log2f(colsum[q]);
}

// ---- row max of affine args: wave = 16 rows, 1KB reads, 1 atomic/block ----
// grid (S/64, z), block 256 (4 waves)
__global__ __launch_bounds__(256) void rowmax_kernel(
    const ushort_t* __restrict__ sim, const float2* __restrict__ coef,
    float* __restrict__ acc, int S, size_t simStride) {
    int z = blockIdx.y;
    sim += (size_t)z * simStride; coef += (size_t)z * S;
    int wave = threadIdx.x >> 6, lane = threadIdx.x & 63;
    int lm = lane & 15;
    int g = blockIdx.x * 4 + wave;          // row-group: 16 rows
    int by = g >> 3, pw = (g >> 2) & 1, t = g & 3;
    int nQB = S >> 7;

    f32x4 m = {-INFINITY, -INFINITY, -INFINITY, -INFINITY};
    for (int bx = 0; bx < nQB; bx++) {
        const ushort_t* tb = sim + ((size_t)(by * nQB + bx)) * 16384 + lane * 8;
#pragma unroll
        for (int qw = 0; qw < 2; qw++) {
            int slot = qw * 2 + pw;
#pragma unroll
            for (int U = 0; U < 2; U++) {
                ushort8_t w = *(const ushort8_t*)(tb + slot * 4096 + (t * 2 + U) * 512);
#pragma unroll
                for (int du = 0; du < 2; du++) {
                    float2 cc = coef[bx * 128 + qw * 64 + U * 32 + du * 16 + lm];
#pragma unroll
                    for (int r = 0; r < 4; r++)
                        m[r] = fmaxf(m[r], cc.x + cc.y * bf2f(w.v[du * 4 + r]));
                }
            }
        }
    }
    // reduce across lm lanes (same quad = same rows)
#pragma unroll
    for (int off = 1; off < 16; off <<= 1)
#pragma unroll
        for (int e = 0; e < 4; e++)
            m[e] = fmaxf(m[e], __shfl_xor(m[e], off, 64));
    __shared__ float partial[16];
    if (lm == 0)
        partial[wave * 4 + (lane >> 4)] = exp2f(m[0]) + exp2f(m[1]) + exp2f(m[2]) + exp2f(m[3]);
    __syncthreads();
    if (threadIdx.x == 0) {
        float s = 0.f;
#pragma unroll
        for (int i = 0; i < 16; i++) s += partial[i];
        atomicAdd(acc + z, s);
    }
}

__global__ void finalize_kernel(const float* __restrict__ acc, float* __restrict__ out) {
    float loss = 0.f;
    for (int b = 0; b < 4; b++) loss += -logf(acc[b] * (1.f / 4096.f));
    for (int b = 0; b < 4; b++) loss += -2.f * logf(acc[4 + b] * (1.f / 1024.f));
    out[0] = loss;
}

extern "C" void kernel_launch(void* const* d_in, const int* in_sizes, int n_in,
                              void* d_out, int out_size, void* d_ws, size_t ws_size,
                              hipStream_t stream) {
    const float* gen3 = (const float*)d_in[0];
    const float* tar3 = (const float*)d_in[1];
    const float* gen4 = (const float*)d_in[2];
    const float* tar4 = (const float*)d_in[3];

    const int zB3 = (ws_size >= (size_t)170 * 1024 * 1024) ? 4 : 2;

    char* wsb = (char*)d_ws;
    size_t off = 0;
    auto alloc = [&](size_t bytes) {
        void* p = wsb + off;
        off += (bytes + 255) & ~(size_t)255;
        return p;
    };
    ushort_t* sim = (ushort_t*)alloc((size_t)zB3 * 4096 * 4096 * 2);
    ushort_t* gnT = (ushort_t*)alloc((size_t)zB3 * 4096 * 256 * 2);
    ushort_t* tnT = (ushort_t*)alloc((size_t)zB3 * 4096 * 256 * 2);
    float* cmPart = (float*)alloc((size_t)zB3 * 64 * 4096 * 4);
    float2* coef = (float2*)alloc(4 * 4096 * sizeof(float2));
    float* colsum = (float*)alloc(4 * 4096 * 4);
    float* mean = (float*)alloc(4 * 4096 * 4);
    float* rg = (float*)alloc(4 * 4096 * 4);
    float* rt = (float*)alloc(4 * 4096 * 4);
    float* acc = (float*)alloc(64 * 4);

    // ---- layer 0: C=256, S=4096 ----
    {
        const int C = 256, S = 4096, R = 2 * (S / 128);
        stats_kernel<<<dim3(S / 16, 4), 256, 0, stream>>>(gen3, tar3, mean, rg, rt, C, S);
        for (int r0 = 0; r0 < 4; r0 += zB3) {
            apply_kernel<<<dim3(S / 64, C / 64, zB3), 256, 0, stream>>>(
                gen3, tar3, mean, rg, rt, gnT, tnT, C, S, r0);
            gemm_mfma<256><<<dim3(S / 128, S / 128, zB3), 256, 0, stream>>>(
                tnT, gnT, sim, cmPart, S, (size_t)S * C, (size_t)S * S, (size_t)R * S);
            colmax_reduce<<<dim3(S / 256, zB3), 256, 0, stream>>>(
                cmPart, coef, colsum, acc + r0, S, R, (size_t)R * S);
            colsum_kernel<<<dim3(S / 128, S / 512, zB3), 256, 0, stream>>>(
                sim, coef, colsum, S, (size_t)S * S);
            coef_fold<<<dim3(S / 256, zB3), 256, 0, stream>>>(coef, colsum, S);
            rowmax_kernel<<<dim3(S / 64, zB3), 256, 0, stream>>>(
                sim, coef, acc + r0, S, (size_t)S * S);
        }
    }
    // ---- layer 1: C=512, S=1024, z=4 ----
    {
        const int C = 512, S = 1024, R = 2 * (S / 128);
        stats_kernel<<<dim3(S / 16, 4), 256, 0, stream>>>(gen4, tar4, mean, rg, rt, C, S);
        apply_kernel<<<dim3(S / 64, C / 64, 4), 256, 0, stream>>>(
            gen4, tar4, mean, rg, rt, gnT, tnT, C, S, 0);
        gemm_mfma<512><<<dim3(S / 128, S / 128, 4), 256, 0, stream>>>(
            tnT, gnT, sim, cmPart, S, (size_t)S * C, (size_t)S * S, (size_t)R * S);
        colmax_reduce<<<dim3(S / 256, 4), 256, 0, stream>>>(
            cmPart, coef, colsum, acc + 4, S, R, (size_t)R * S);
        colsum_kernel<<<dim3(S / 128, S / 512, 4), 256, 0, stream>>>(
            sim, coef, colsum, S, (size_t)S * S);
        coef_fold<<<dim3(S / 256, 4), 256, 0, stream>>>(coef, colsum, S);
        rowmax_kernel<<<dim3(S / 64, 4), 256, 0, stream>>>(
            sim, coef, acc + 4, S, (size_t)S * S);
    }
    finalize_kernel<<<1, 1, 0, stream>>>(acc, (float*)d_out);
}